// Round 2
// baseline (6555.702 us; speedup 1.0000x reference)
//
#include <hip/hip_runtime.h>
#include <math.h>

namespace {
constexpr int CIN  = 128;
constexpr int NN   = 2048;
constexpr int KK   = 16;
constexpr int DIM  = 256;
constexpr int NPOS = 3;
constexpr int PH   = 64;
constexpr int AH   = 1024;
constexpr float EPSV = 1e-5f;
}

// 16 FMAs: acc[k] += w * base[k], base read as 4x float4 (broadcast LDS reads)
#define FMA16_(W, BASE, ACC) do { \
    const float4* _p = (const float4*)(BASE); \
    float4 _a = _p[0], _b = _p[1], _c = _p[2], _d = _p[3]; \
    ACC[0]  = fmaf(W, _a.x, ACC[0]);  ACC[1]  = fmaf(W, _a.y, ACC[1]); \
    ACC[2]  = fmaf(W, _a.z, ACC[2]);  ACC[3]  = fmaf(W, _a.w, ACC[3]); \
    ACC[4]  = fmaf(W, _b.x, ACC[4]);  ACC[5]  = fmaf(W, _b.y, ACC[5]); \
    ACC[6]  = fmaf(W, _b.z, ACC[6]);  ACC[7]  = fmaf(W, _b.w, ACC[7]); \
    ACC[8]  = fmaf(W, _c.x, ACC[8]);  ACC[9]  = fmaf(W, _c.y, ACC[9]); \
    ACC[10] = fmaf(W, _c.z, ACC[10]); ACC[11] = fmaf(W, _c.w, ACC[11]); \
    ACC[12] = fmaf(W, _d.x, ACC[12]); ACC[13] = fmaf(W, _d.y, ACC[13]); \
    ACC[14] = fmaf(W, _d.z, ACC[14]); ACC[15] = fmaf(W, _d.w, ACC[15]); \
} while (0)

// 32 FMAs sharing one set of 16 broadcast-read values across two weight scalars
#define FMA16_2(WA, WB, BASE, ACCA, ACCB) do { \
    const float4* _p = (const float4*)(BASE); \
    float4 _a = _p[0], _b = _p[1], _c = _p[2], _d = _p[3]; \
    ACCA[0]  = fmaf(WA, _a.x, ACCA[0]);  ACCB[0]  = fmaf(WB, _a.x, ACCB[0]); \
    ACCA[1]  = fmaf(WA, _a.y, ACCA[1]);  ACCB[1]  = fmaf(WB, _a.y, ACCB[1]); \
    ACCA[2]  = fmaf(WA, _a.z, ACCA[2]);  ACCB[2]  = fmaf(WB, _a.z, ACCB[2]); \
    ACCA[3]  = fmaf(WA, _a.w, ACCA[3]);  ACCB[3]  = fmaf(WB, _a.w, ACCB[3]); \
    ACCA[4]  = fmaf(WA, _b.x, ACCA[4]);  ACCB[4]  = fmaf(WB, _b.x, ACCB[4]); \
    ACCA[5]  = fmaf(WA, _b.y, ACCA[5]);  ACCB[5]  = fmaf(WB, _b.y, ACCB[5]); \
    ACCA[6]  = fmaf(WA, _b.z, ACCA[6]);  ACCB[6]  = fmaf(WB, _b.z, ACCB[6]); \
    ACCA[7]  = fmaf(WA, _b.w, ACCA[7]);  ACCB[7]  = fmaf(WB, _b.w, ACCB[7]); \
    ACCA[8]  = fmaf(WA, _c.x, ACCA[8]);  ACCB[8]  = fmaf(WB, _c.x, ACCB[8]); \
    ACCA[9]  = fmaf(WA, _c.y, ACCA[9]);  ACCB[9]  = fmaf(WB, _c.y, ACCB[9]); \
    ACCA[10] = fmaf(WA, _c.z, ACCA[10]); ACCB[10] = fmaf(WB, _c.z, ACCB[10]); \
    ACCA[11] = fmaf(WA, _c.w, ACCA[11]); ACCB[11] = fmaf(WB, _c.w, ACCB[11]); \
    ACCA[12] = fmaf(WA, _d.x, ACCA[12]); ACCB[12] = fmaf(WB, _d.x, ACCB[12]); \
    ACCA[13] = fmaf(WA, _d.y, ACCA[13]); ACCB[13] = fmaf(WB, _d.y, ACCB[13]); \
    ACCA[14] = fmaf(WA, _d.z, ACCA[14]); ACCB[14] = fmaf(WB, _d.z, ACCB[14]); \
    ACCA[15] = fmaf(WA, _d.w, ACCA[15]); ACCB[15] = fmaf(WB, _d.w, ACCB[15]); \
} while (0)

__global__ __launch_bounds__(256, 2)
void pt_fused_kernel(const float* __restrict__ key, const float* __restrict__ values,
                     const float* __restrict__ pos,
                     const float* __restrict__ Wk,  const float* __restrict__ bk,
                     const float* __restrict__ Wq,  const float* __restrict__ bq,
                     const float* __restrict__ Wv,  const float* __restrict__ bv,
                     const float* __restrict__ Wp1, const float* __restrict__ bp1,
                     const float* __restrict__ pg,  const float* __restrict__ pb,
                     const float* __restrict__ pm,  const float* __restrict__ pvv,
                     const float* __restrict__ Wp2, const float* __restrict__ bp2,
                     const float* __restrict__ Wa1, const float* __restrict__ ba1,
                     const float* __restrict__ ag,  const float* __restrict__ ab,
                     const float* __restrict__ am,  const float* __restrict__ av,
                     const float* __restrict__ Wa2, const float* __restrict__ ba2,
                     const float* __restrict__ We,  const float* __restrict__ be,
                     float* __restrict__ out)
{
    // LDS: 256+64+256+2048+4096+8192 floats = 58.25 KB -> 2 blocks/CU
    __shared__ __align__(16) float q_s[DIM];
    __shared__ __align__(16) float h1_s[PH];
    __shared__ __align__(16) float agg_s[DIM];
    __shared__ __align__(16) float kv_s[CIN * KK];   // key, then re-staged with values
    __shared__ __align__(16) float X_s[DIM * KK];    // attn_in, [c][k]
    __shared__ __align__(16) float hr_s[512 * KK];   // layer1 relu output chunk, [jj][k]

    const int t  = threadIdx.x;
    const int bn = blockIdx.x;
    const int b  = bn >> 11;      // / 2048
    const int n  = bn & (NN - 1);

    // ---- q (per (b,n), k-independent); thread t owns channel o=t ----
    const float p0 = pos[(b * NPOS + 0) * NN + n];
    const float p1 = pos[(b * NPOS + 1) * NN + n];
    const float p2 = pos[(b * NPOS + 2) * NN + n];
    const float qv = fmaf(Wq[t * NPOS + 0], p0,
                     fmaf(Wq[t * NPOS + 1], p1,
                     fmaf(Wq[t * NPOS + 2], p2, bq[t])));
    q_s[t] = qv;

    // ---- stage key[b,:,n,:] into LDS (each 16-float row = one aligned 64B line) ----
    {
        const float* kb = key + ((size_t)b * CIN * NN + n) * KK;
        #pragma unroll
        for (int m2 = 0; m2 < (CIN * KK) / 256; ++m2) {
            const int idx = t + m2 * 256;
            const int c = idx >> 4, k = idx & 15;
            kv_s[idx] = kb[(size_t)c * NN * KK + k];
        }
    }
    __syncthreads();

    // ---- h1 = relu(bn(Wp1 @ q + bp1)) : 64 channels ----
    if (t < PH) {
        float acc = 0.f;
        #pragma unroll 8
        for (int c = 0; c < DIM; ++c) acc = fmaf(Wp1[t * DIM + c], q_s[c], acc);
        acc += bp1[t];
        const float sc = pg[t] * rsqrtf(pvv[t] + EPSV);
        const float h  = fmaf(acc, sc, pb[t] - pm[t] * sc);
        h1_s[t] = fmaxf(h, 0.f);
    }
    __syncthreads();

    // ---- pe[o=t] (k-independent) ----
    float pe;
    {
        float acc = 0.f;
        #pragma unroll 8
        for (int j = 0; j < PH; ++j) acc = fmaf(Wp2[t * PH + j], h1_s[j], acc);
        pe = acc + bp2[t];
    }

    // ---- kf[o=t][k] and X = (q - kf + 1) * pe ----
    {
        float acc[KK];
        #pragma unroll
        for (int k = 0; k < KK; ++k) acc[k] = 0.f;
        const float* __restrict__ wr = Wk + t * CIN;
        #pragma unroll 4
        for (int c = 0; c < CIN; ++c) {
            const float w = wr[c];
            FMA16_(w, kv_s + c * KK, acc);
        }
        const float bkt = bk[t];
        #pragma unroll
        for (int k = 0; k < KK; ++k)
            X_s[t * KK + k] = (qv - (acc[k] + bkt) + 1.f) * pe;
    }
    __syncthreads();

    // ---- re-stage values into kv_s (key is dead); loads overlap layer1 compute ----
    {
        const float* vb = values + ((size_t)b * CIN * NN + n) * KK;
        #pragma unroll
        for (int m2 = 0; m2 < (CIN * KK) / 256; ++m2) {
            const int idx = t + m2 * 256;
            const int c = idx >> 4, k = idx & 15;
            kv_s[idx] = vb[(size_t)c * NN * KK + k];
        }
    }

    // ---- attn MLP: Y[o=t][k] = Wa2 @ relu(bn(Wa1 @ X + ba1))  (ba2 cancels in softmax) ----
    float Y[KK];
    #pragma unroll
    for (int k = 0; k < KK; ++k) Y[k] = 0.f;

    #pragma unroll 1
    for (int jc = 0; jc < 2; ++jc) {
        // layer1: this thread computes j0 = jc*512 + t and j1 = j0 + 256 (shared X reads)
        {
            float a0[KK], a1[KK];
            #pragma unroll
            for (int k = 0; k < KK; ++k) { a0[k] = 0.f; a1[k] = 0.f; }
            const int j0 = jc * 512 + t;
            const int j1 = j0 + 256;
            const float* __restrict__ w0 = Wa1 + (size_t)j0 * DIM;
            const float* __restrict__ w1 = Wa1 + (size_t)j1 * DIM;
            #pragma unroll 2
            for (int c = 0; c < DIM; ++c) {
                const float wa = w0[c];
                const float wb = w1[c];
                FMA16_2(wa, wb, X_s + c * KK, a0, a1);
            }
            const float sc0 = ag[j0] * rsqrtf(av[j0] + EPSV);
            const float sh0 = ab[j0] - am[j0] * sc0;
            const float bb0 = ba1[j0];
            const float sc1 = ag[j1] * rsqrtf(av[j1] + EPSV);
            const float sh1 = ab[j1] - am[j1] * sc1;
            const float bb1 = ba1[j1];
            #pragma unroll
            for (int k = 0; k < KK; ++k) {
                hr_s[t * KK + k]         = fmaxf(fmaf(a0[k] + bb0, sc0, sh0), 0.f);
                hr_s[(t + 256) * KK + k] = fmaxf(fmaf(a1[k] + bb1, sc1, sh1), 0.f);
            }
        }
        __syncthreads();
        // layer2: accumulate Y[o=t] over this 512-j chunk
        {
            const float* __restrict__ w = Wa2 + (size_t)t * AH + jc * 512;
            #pragma unroll 4
            for (int jj = 0; jj < 512; ++jj) {
                const float wv2 = w[jj];
                FMA16_(wv2, hr_s + jj * KK, Y);
            }
        }
        __syncthreads();   // before next chunk overwrites hr_s
    }

    // ---- softmax over k (entirely per-thread) ----
    {
        float m = Y[0];
        #pragma unroll
        for (int k = 1; k < KK; ++k) m = fmaxf(m, Y[k]);
        float s = 0.f;
        #pragma unroll
        for (int k = 0; k < KK; ++k) { Y[k] = expf(Y[k] - m); s += Y[k]; }
        const float inv = 1.f / s;
        #pragma unroll
        for (int k = 0; k < KK; ++k) Y[k] *= inv;
    }

    // ---- v[o=t][k] = Wv @ values + bv ; agg[o] = sum_k attn * (v + pe) ----
    {
        float acc[KK];
        #pragma unroll
        for (int k = 0; k < KK; ++k) acc[k] = 0.f;
        const float* __restrict__ wr = Wv + t * CIN;
        #pragma unroll 4
        for (int c = 0; c < CIN; ++c) {
            const float w = wr[c];
            FMA16_(w, kv_s + c * KK, acc);
        }
        const float bvt = bv[t];
        float aggv = 0.f;
        #pragma unroll
        for (int k = 0; k < KK; ++k) aggv = fmaf(Y[k], acc[k] + bvt + pe, aggv);
        agg_s[t] = aggv;
    }
    __syncthreads();

    // ---- out[b, o=t, n] = We @ agg + be ----
    {
        float acc = 0.f;
        const float* __restrict__ wr = We + t * DIM;
        const float4* __restrict__ a4 = (const float4*)agg_s;
        #pragma unroll 4
        for (int c4 = 0; c4 < DIM / 4; ++c4) {
            const float4 a = a4[c4];
            acc = fmaf(wr[c4 * 4 + 0], a.x, acc);
            acc = fmaf(wr[c4 * 4 + 1], a.y, acc);
            acc = fmaf(wr[c4 * 4 + 2], a.z, acc);
            acc = fmaf(wr[c4 * 4 + 3], a.w, acc);
        }
        out[((size_t)(b * DIM + t)) * NN + n] = acc + be[t];
    }
}

extern "C" void kernel_launch(void* const* d_in, const int* in_sizes, int n_in,
                              void* d_out, int out_size, void* d_ws, size_t ws_size,
                              hipStream_t stream) {
    const float* key    = (const float*)d_in[0];
    const float* values = (const float*)d_in[1];
    const float* pos    = (const float*)d_in[2];
    const float* Wk     = (const float*)d_in[3];
    const float* bk     = (const float*)d_in[4];
    const float* Wq     = (const float*)d_in[5];
    const float* bq     = (const float*)d_in[6];
    const float* Wv     = (const float*)d_in[7];
    const float* bv     = (const float*)d_in[8];
    const float* Wp1    = (const float*)d_in[9];
    const float* bp1    = (const float*)d_in[10];
    const float* pg     = (const float*)d_in[11];
    const float* pb     = (const float*)d_in[12];
    const float* pm     = (const float*)d_in[13];
    const float* pvv    = (const float*)d_in[14];
    const float* Wp2    = (const float*)d_in[15];
    const float* bp2    = (const float*)d_in[16];
    const float* Wa1    = (const float*)d_in[17];
    const float* ba1    = (const float*)d_in[18];
    const float* ag     = (const float*)d_in[19];
    const float* ab     = (const float*)d_in[20];
    const float* am     = (const float*)d_in[21];
    const float* av     = (const float*)d_in[22];
    const float* Wa2    = (const float*)d_in[23];
    const float* ba2    = (const float*)d_in[24];
    const float* We     = (const float*)d_in[25];
    const float* be     = (const float*)d_in[26];
    (void)ba2; (void)in_sizes; (void)n_in; (void)d_ws; (void)ws_size; (void)out_size;

    dim3 grid(4 * 2048);
    dim3 block(256);
    hipLaunchKernelGGL(pt_fused_kernel, grid, block, 0, stream,
                       key, values, pos, Wk, bk, Wq, bq, Wv, bv,
                       Wp1, bp1, pg, pb, pm, pvv, Wp2, bp2,
                       Wa1, ba1, ag, ab, am, av, Wa2, ba2, We, be,
                       (float*)d_out);
}

// Round 3
// 480.819 us; speedup vs baseline: 13.6345x; 13.6345x over previous
//
#include <hip/hip_runtime.h>
#include <math.h>

typedef __attribute__((ext_vector_type(8))) short bf16x8;
typedef __attribute__((ext_vector_type(4))) float f32x4;

namespace {
constexpr int NN   = 2048;
constexpr float EPSV = 1e-5f;

// ---- workspace layout (bytes) ----
constexpr size_t WK_O   = 0;        // ushort[256*128]  Wk  bf16 [o][c]
constexpr size_t WV_O   = 65536;    // ushort[256*128]  Wv  bf16 [o][c]
constexpr size_t B1F_O  = 131072;   // float[1024]      folded bn bias for layer1
constexpr size_t WEP_O  = 135168;   // ushort[256*256]  We  bf16 [o][c]
constexpr size_t WA1I_O = 266240;   // ushort[262144]   Wa1 folded, 16 chunk images (32KB, swizzled)
constexpr size_t WA2I_O = 790528;   // ushort[262144]   Wa2, 16 chunk images (32KB, swizzled)
constexpr size_t WP1Q_O = 1314816;  // float[64*4]      folded Wp1@Wq (+bias in .w)
constexpr size_t SC_O   = 1315840;  // float[1024]      attn bn scale
constexpr size_t WS_TOTAL = 1319936;

// ---- LDS layout (bytes) ----
constexpr int X_OFF   = 0;        // X [128m][256c] bf16 stride 512, swz ^((m&7)<<4); also keybf [128][128] stride 256; also aggbf rows 0..7
constexpr int WC_OFF  = 65536;    // Wa1 chunk image 32KB; later valbf [128][128] stride 256 swz
constexpr int WA2C_OFF= 98304;    // Wa2 chunk image 32KB
constexpr int HR_OFF  = 131072;   // 4 waves * 4KB : [32m][64j] bf16 stride 128, swz
constexpr int PE_OFF  = 147456;   // pe bf16 [8n][256] stride 512
constexpr int H1_OFF  = 151552;   // h1 f32 [64ph][8n]
constexpr int POS_OFF = 153600;   // pos f32 [8n][4]
constexpr int LDS_TOTAL = 153728;
}

__device__ __forceinline__ unsigned short f2bf(float x) {
    unsigned u = __float_as_uint(x);
    unsigned r = (u + 0x7FFFu + ((u >> 16) & 1u)) >> 16;
    return (unsigned short)r;
}
__device__ __forceinline__ float bf2f(unsigned short h) {
    return __uint_as_float(((unsigned)h) << 16);
}

// ================= prep kernels =================

// blocks 0-3: attn bn fold (sc, b1f). block 4: pe-path fold (Wp1@Wq etc).
__global__ void prep_sc(const float* __restrict__ ag,  const float* __restrict__ ab,
                        const float* __restrict__ am,  const float* __restrict__ av,
                        const float* __restrict__ ba1,
                        const float* __restrict__ Wp1, const float* __restrict__ Wq,
                        const float* __restrict__ bq,  const float* __restrict__ bp1,
                        const float* __restrict__ pg,  const float* __restrict__ pb,
                        const float* __restrict__ pm,  const float* __restrict__ pv,
                        char* __restrict__ ws)
{
    const int t = threadIdx.x, blk = blockIdx.x;
    float* b1f  = (float*)(ws + B1F_O);
    float* sc_s = (float*)(ws + SC_O);
    float* wp1q = (float*)(ws + WP1Q_O);
    if (blk < 4) {
        int j = blk * 256 + t;
        float sc = ag[j] * rsqrtf(av[j] + EPSV);
        sc_s[j] = sc;
        b1f[j] = ba1[j] * sc + ab[j] - am[j] * sc;
    } else if (t < 64) {
        int ph = t;
        float scp = pg[ph] * rsqrtf(pv[ph] + EPSV);
        float a0 = 0.f, a1 = 0.f, a2 = 0.f, abv = 0.f;
        for (int c = 0; c < 256; ++c) {
            float wv = Wp1[ph * 256 + c];
            a0 = fmaf(wv, Wq[c * 3 + 0], a0);
            a1 = fmaf(wv, Wq[c * 3 + 1], a1);
            a2 = fmaf(wv, Wq[c * 3 + 2], a2);
            abv = fmaf(wv, bq[c], abv);
        }
        wp1q[ph * 4 + 0] = scp * a0;
        wp1q[ph * 4 + 1] = scp * a1;
        wp1q[ph * 4 + 2] = scp * a2;
        wp1q[ph * 4 + 3] = scp * (abv + bp1[ph]) + (pb[ph] - pm[ph] * scp);
    }
}

// grid 2560*256 : bf16 conversions + swizzled chunk images
__global__ void prep_cvt(const float* __restrict__ Wk, const float* __restrict__ Wv,
                         const float* __restrict__ We, const float* __restrict__ Wa1,
                         const float* __restrict__ Wa2, char* __restrict__ ws)
{
    const int idx = blockIdx.x * 256 + threadIdx.x;
    unsigned short* wk  = (unsigned short*)(ws + WK_O);
    unsigned short* wv  = (unsigned short*)(ws + WV_O);
    unsigned short* wep = (unsigned short*)(ws + WEP_O);
    unsigned short* w1i = (unsigned short*)(ws + WA1I_O);
    unsigned short* w2i = (unsigned short*)(ws + WA2I_O);
    const float* sc_s = (const float*)(ws + SC_O);
    if (idx < 32768) {
        wk[idx] = f2bf(Wk[idx]);
    } else if (idx < 65536) {
        int i = idx - 32768; wv[i] = f2bf(Wv[i]);
    } else if (idx < 131072) {
        int i = idx - 65536; wep[i] = f2bf(We[i]);
    } else if (idx < 393216) {
        int e = idx - 131072;
        int j = e >> 8, c = e & 255;
        float val = sc_s[j] * Wa1[e];
        int cc = j >> 6, jl = j & 63;
        int byte = cc * 32768 + (((jl << 9) + (c << 1)) ^ ((jl & 7) << 4));
        w1i[byte >> 1] = f2bf(val);
    } else {
        int e = idx - 393216;
        int o = e >> 10, j = e & 1023;
        int cc = j >> 6, jl = j & 63;
        int byte = cc * 32768 + (((o << 7) + (jl << 1)) ^ ((o & 7) << 4));
        w2i[byte >> 1] = f2bf(Wa2[e]);
    }
}

// ================= main fused kernel =================
// 1024 blocks (4 b * 256 n-tiles of 8), 256 threads = 4 waves, wave owns 32 MFMA rows.
__global__ __launch_bounds__(256, 1)
void pt_main(const float* __restrict__ key, const float* __restrict__ values,
             const float* __restrict__ pos,
             const float* __restrict__ Wq,  const float* __restrict__ bq,
             const float* __restrict__ bk,  const float* __restrict__ bv,
             const float* __restrict__ Wp2, const float* __restrict__ bp2,
             const float* __restrict__ be,
             const char* __restrict__ ws,
             float* __restrict__ outp)
{
    extern __shared__ char sm[];
    const int t = threadIdx.x;
    const int w = t >> 6, l = t & 63;
    const int l15 = l & 15, lg = l >> 4;
    const int blk = blockIdx.x;
    const int b = blk >> 8;
    const int n0 = (blk & 255) * 8;
    const int wm0 = w * 32;

    const unsigned short* wkp = (const unsigned short*)(ws + WK_O);
    const unsigned short* wvp = (const unsigned short*)(ws + WV_O);
    const unsigned short* wep = (const unsigned short*)(ws + WEP_O);
    const float* b1f  = (const float*)(ws + B1F_O);
    const float* wp1q = (const float*)(ws + WP1Q_O);

    // ---- pos staging ----
    if (t < 24) {
        int nl = t / 3, p = t % 3;
        *(float*)(sm + POS_OFF + nl * 16 + p * 4) = pos[(b * 3 + p) * NN + n0 + nl];
    }
    // ---- key staging -> keybf LDS [128m][128c] bf16, stride 256, swz ----
    {
        #pragma unroll
        for (int it = 0; it < 16; ++it) {
            int i = it * 256 + t;
            int clow = i & 7, k4 = (i >> 3) & 3, nl = (i >> 5) & 7, chigh = i >> 8;
            int c = chigh * 8 + clow;
            const float4 v = *(const float4*)(key + ((size_t)(b * 128 + c) * NN + (n0 + nl)) * 16 + k4 * 4);
            int m = nl * 16 + k4 * 4;
            #pragma unroll
            for (int j = 0; j < 4; ++j) {
                int mm = m + j;
                int byte = ((mm << 8) + (c << 1)) ^ ((mm & 7) << 4);
                float fj = (j == 0) ? v.x : (j == 1) ? v.y : (j == 2) ? v.z : v.w;
                *(unsigned short*)(sm + X_OFF + byte) = f2bf(fj);
            }
        }
    }
    __syncthreads();

    // ---- h1[ph][n] = relu(folded pe-path layer1) ----
    #pragma unroll
    for (int rep = 0; rep < 2; ++rep) {
        int idx = rep * 256 + t;
        int ph = idx >> 3, nl = idx & 7;
        const float4 wq4 = *(const float4*)(wp1q + ph * 4);
        float p0 = *(const float*)(sm + POS_OFF + nl * 16 + 0);
        float p1 = *(const float*)(sm + POS_OFF + nl * 16 + 4);
        float p2 = *(const float*)(sm + POS_OFF + nl * 16 + 8);
        float h = fmaf(wq4.x, p0, fmaf(wq4.y, p1, fmaf(wq4.z, p2, wq4.w)));
        *(float*)(sm + H1_OFF + ph * 32 + nl * 4) = fmaxf(h, 0.f);
    }
    __syncthreads();

    // ---- pe[n][o=t] ----
    {
        float acc[8];
        #pragma unroll
        for (int n = 0; n < 8; ++n) acc[n] = 0.f;
        #pragma unroll 4
        for (int j = 0; j < 64; ++j) {
            float wv2 = Wp2[t * 64 + j];
            float4 ha = *(const float4*)(sm + H1_OFF + j * 32);
            float4 hb = *(const float4*)(sm + H1_OFF + j * 32 + 16);
            acc[0] = fmaf(wv2, ha.x, acc[0]); acc[1] = fmaf(wv2, ha.y, acc[1]);
            acc[2] = fmaf(wv2, ha.z, acc[2]); acc[3] = fmaf(wv2, ha.w, acc[3]);
            acc[4] = fmaf(wv2, hb.x, acc[4]); acc[5] = fmaf(wv2, hb.y, acc[5]);
            acc[6] = fmaf(wv2, hb.z, acc[6]); acc[7] = fmaf(wv2, hb.w, acc[7]);
        }
        float bp = bp2[t];
        #pragma unroll
        for (int n = 0; n < 8; ++n)
            *(unsigned short*)(sm + PE_OFF + n * 512 + t * 2) = f2bf(acc[n] + bp);
    }

    // ---- kf GEMM: A = keybf, B = Wk' (global, L2) ----
    bf16x8 ak[2][4];
    #pragma unroll
    for (int mt = 0; mt < 2; ++mt)
        #pragma unroll
        for (int kt = 0; kt < 4; ++kt) {
            int m = wm0 + mt * 16 + l15, c = kt * 32 + lg * 8;
            ak[mt][kt] = *(const bf16x8*)(sm + X_OFF + (((m << 8) + (c << 1)) ^ ((m & 7) << 4)));
        }
    f32x4 zf = {0.f, 0.f, 0.f, 0.f};
    f32x4 kacc[2][16];
    #pragma unroll
    for (int mt = 0; mt < 2; ++mt)
        #pragma unroll
        for (int ot = 0; ot < 16; ++ot) kacc[mt][ot] = zf;
    #pragma unroll
    for (int ot = 0; ot < 16; ++ot) {
        #pragma unroll
        for (int kt = 0; kt < 4; ++kt) {
            int o = ot * 16 + l15, c = kt * 32 + lg * 8;
            bf16x8 bfr = *(const bf16x8*)(wkp + o * 128 + c);
            kacc[0][ot] = __builtin_amdgcn_mfma_f32_16x16x32_bf16(ak[0][kt], bfr, kacc[0][ot], 0, 0, 0);
            kacc[1][ot] = __builtin_amdgcn_mfma_f32_16x16x32_bf16(ak[1][kt], bfr, kacc[1][ot], 0, 0, 0);
        }
    }
    __syncthreads();   // all keybf reads done before X overwrites region

    // ---- X epilogue: X[m][o] = (q - kf + 1)*pe, bf16 swizzled ----
    #pragma unroll
    for (int mt = 0; mt < 2; ++mt) {
        const int nl = 2 * w + mt;
        float p0 = *(const float*)(sm + POS_OFF + nl * 16 + 0);
        float p1 = *(const float*)(sm + POS_OFF + nl * 16 + 4);
        float p2 = *(const float*)(sm + POS_OFF + nl * 16 + 8);
        #pragma unroll
        for (int ot = 0; ot < 16; ++ot) {
            int o = ot * 16 + l15;
            float q = fmaf(Wq[o * 3 + 0], p0, fmaf(Wq[o * 3 + 1], p1, fmaf(Wq[o * 3 + 2], p2, bq[o])));
            float pe = bf2f(*(const unsigned short*)(sm + PE_OFF + nl * 512 + o * 2));
            float bko = bk[o];
            #pragma unroll
            for (int r = 0; r < 4; ++r) {
                int m = wm0 + mt * 16 + lg * 4 + r;
                float x = (q - (kacc[mt][ot][r] + bko) + 1.f) * pe;
                *(unsigned short*)(sm + X_OFF + (((m << 9) + (o << 1)) ^ ((m & 7) << 4))) = f2bf(x);
            }
        }
    }

    // ---- attn MLP over 16 chunks of 64 j ----
    f32x4 Y[2][16];
    #pragma unroll
    for (int mt = 0; mt < 2; ++mt)
        #pragma unroll
        for (int ot = 0; ot < 16; ++ot) Y[mt][ot] = zf;

    for (int cc = 0; cc < 16; ++cc) {
        if (cc) __syncthreads();          // prior chunk's B-reads complete
        {   // stage both 32KB chunk images (linear copy; images pre-swizzled)
            const float4* s1 = (const float4*)(ws + WA1I_O + (size_t)cc * 32768);
            float4* d1 = (float4*)(sm + WC_OFF);
            const float4* s2 = (const float4*)(ws + WA2I_O + (size_t)cc * 32768);
            float4* d2 = (float4*)(sm + WA2C_OFF);
            #pragma unroll
            for (int i = 0; i < 8; ++i) d1[i * 256 + t] = s1[i * 256 + t];
            #pragma unroll
            for (int i = 0; i < 8; ++i) d2[i * 256 + t] = s2[i * 256 + t];
        }
        __syncthreads();

        // layer1: hr = relu(Wa1c @ X + b1f)   (bn folded)
        #pragma unroll
        for (int mt = 0; mt < 2; ++mt) {
            bf16x8 ax[8];
            #pragma unroll
            for (int kt = 0; kt < 8; ++kt) {
                int m = wm0 + mt * 16 + l15, c = kt * 32 + lg * 8;
                ax[kt] = *(const bf16x8*)(sm + X_OFF + (((m << 9) + (c << 1)) ^ ((m & 7) << 4)));
            }
            #pragma unroll
            for (int jt = 0; jt < 4; ++jt) {
                f32x4 acc = zf;
                #pragma unroll
                for (int kt = 0; kt < 8; ++kt) {
                    int jl = jt * 16 + l15, c2 = kt * 32 + lg * 8;
                    bf16x8 bw = *(const bf16x8*)(sm + WC_OFF + (((jl << 9) + (c2 << 1)) ^ ((jl & 7) << 4)));
                    acc = __builtin_amdgcn_mfma_f32_16x16x32_bf16(ax[kt], bw, acc, 0, 0, 0);
                }
                float b1v = b1f[cc * 64 + jt * 16 + l15];
                #pragma unroll
                for (int r = 0; r < 4; ++r) {
                    int ml = mt * 16 + lg * 4 + r, jl = jt * 16 + l15;
                    float hv = fmaxf(acc[r] + b1v, 0.f);
                    *(unsigned short*)(sm + HR_OFF + w * 4096 + (((ml << 7) + (jl << 1)) ^ ((ml & 7) << 4))) = f2bf(hv);
                }
            }
        }
        // layer2: Y += hr @ Wa2c^T
        #pragma unroll
        for (int mt = 0; mt < 2; ++mt) {
            bf16x8 ah[2];
            #pragma unroll
            for (int kt = 0; kt < 2; ++kt) {
                int ml = mt * 16 + l15, jl = kt * 32 + lg * 8;
                ah[kt] = *(const bf16x8*)(sm + HR_OFF + w * 4096 + (((ml << 7) + (jl << 1)) ^ ((ml & 7) << 4)));
            }
            #pragma unroll
            for (int ot = 0; ot < 16; ++ot) {
                #pragma unroll
                for (int kt = 0; kt < 2; ++kt) {
                    int o = ot * 16 + l15, jl = kt * 32 + lg * 8;
                    bf16x8 bw = *(const bf16x8*)(sm + WA2C_OFF + (((o << 7) + (jl << 1)) ^ ((o & 7) << 4)));
                    Y[mt][ot] = __builtin_amdgcn_mfma_f32_16x16x32_bf16(ah[kt], bw, Y[mt][ot], 0, 0, 0);
                }
            }
        }
    }
    __syncthreads();   // all chunk reads done

    // ---- stage values -> valbf in WC region ----
    {
        #pragma unroll
        for (int it = 0; it < 16; ++it) {
            int i = it * 256 + t;
            int clow = i & 7, k4 = (i >> 3) & 3, nl = (i >> 5) & 7, chigh = i >> 8;
            int c = chigh * 8 + clow;
            const float4 v = *(const float4*)(values + ((size_t)(b * 128 + c) * NN + (n0 + nl)) * 16 + k4 * 4);
            int m = nl * 16 + k4 * 4;
            #pragma unroll
            for (int j = 0; j < 4; ++j) {
                int mm = m + j;
                int byte = ((mm << 8) + (c << 1)) ^ ((mm & 7) << 4);
                float fj = (j == 0) ? v.x : (j == 1) ? v.y : (j == 2) ? v.z : v.w;
                *(unsigned short*)(sm + WC_OFF + byte) = f2bf(fj);
            }
        }
    }

    // ---- softmax over k (in registers; k = lg*4 + r within each (mt,ot)) ----
    #pragma unroll
    for (int mt = 0; mt < 2; ++mt) {
        #pragma unroll
        for (int ot = 0; ot < 16; ++ot) {
            float mx = fmaxf(fmaxf(Y[mt][ot][0], Y[mt][ot][1]), fmaxf(Y[mt][ot][2], Y[mt][ot][3]));
            mx = fmaxf(mx, __shfl_xor(mx, 16));
            mx = fmaxf(mx, __shfl_xor(mx, 32));
            float e0 = expf(Y[mt][ot][0] - mx), e1 = expf(Y[mt][ot][1] - mx);
            float e2 = expf(Y[mt][ot][2] - mx), e3 = expf(Y[mt][ot][3] - mx);
            float s = e0 + e1 + e2 + e3;
            s += __shfl_xor(s, 16);
            s += __shfl_xor(s, 32);
            float inv = 1.f / s;
            Y[mt][ot][0] = e0 * inv; Y[mt][ot][1] = e1 * inv;
            Y[mt][ot][2] = e2 * inv; Y[mt][ot][3] = e3 * inv;
        }
    }
    __syncthreads();   // valbf visible

    // ---- v GEMM per o-tile + agg = sum_k attn*v + pe -> aggbf (X region rows 0..7) ----
    bf16x8 av_[2][4];
    #pragma unroll
    for (int mt = 0; mt < 2; ++mt)
        #pragma unroll
        for (int kt = 0; kt < 4; ++kt) {
            int m = wm0 + mt * 16 + l15, c = kt * 32 + lg * 8;
            av_[mt][kt] = *(const bf16x8*)(sm + WC_OFF + (((m << 8) + (c << 1)) ^ ((m & 7) << 4)));
        }
    #pragma unroll
    for (int ot = 0; ot < 16; ++ot) {
        int o = ot * 16 + l15;
        f32x4 vacc[2];
        vacc[0] = zf; vacc[1] = zf;
        #pragma unroll
        for (int kt = 0; kt < 4; ++kt) {
            int c = kt * 32 + lg * 8;
            bf16x8 bfr = *(const bf16x8*)(wvp + o * 128 + c);
            vacc[0] = __builtin_amdgcn_mfma_f32_16x16x32_bf16(av_[0][kt], bfr, vacc[0], 0, 0, 0);
            vacc[1] = __builtin_amdgcn_mfma_f32_16x16x32_bf16(av_[1][kt], bfr, vacc[1], 0, 0, 0);
        }
        float bvo = bv[o];
        #pragma unroll
        for (int mt = 0; mt < 2; ++mt) {
            int nl = 2 * w + mt;
            float s = 0.f;
            #pragma unroll
            for (int r = 0; r < 4; ++r)
                s = fmaf(Y[mt][ot][r], vacc[mt][r] + bvo, s);
            s += __shfl_xor(s, 16);
            s += __shfl_xor(s, 32);
            float agg = s + bf2f(*(const unsigned short*)(sm + PE_OFF + nl * 512 + o * 2));
            if (lg == 0)
                *(unsigned short*)(sm + X_OFF + (((nl << 9) + (o << 1)) ^ ((nl & 7) << 4))) = f2bf(agg);
        }
    }
    __syncthreads();

    // ---- We GEMM: out[b][oo][n] ; A = aggbf rows 0..15 (8 real), wave owns 64 oo ----
    bf16x8 aa[8];
    #pragma unroll
    for (int kt = 0; kt < 8; ++kt) {
        int row = l15, c = kt * 32 + lg * 8;
        aa[kt] = *(const bf16x8*)(sm + X_OFF + (((row << 9) + (c << 1)) ^ ((row & 7) << 4)));
    }
    #pragma unroll
    for (int ot = 0; ot < 4; ++ot) {
        int oo = w * 64 + ot * 16 + l15;
        f32x4 acc = zf;
        #pragma unroll
        for (int kt = 0; kt < 8; ++kt) {
            int c = kt * 32 + lg * 8;
            bf16x8 bfr = *(const bf16x8*)(wep + oo * 256 + c);
            acc = __builtin_amdgcn_mfma_f32_16x16x32_bf16(aa[kt], bfr, acc, 0, 0, 0);
        }
        if (lg < 2) {
            float bev = be[oo];
            float4 vv;
            vv.x = acc[0] + bev; vv.y = acc[1] + bev;
            vv.z = acc[2] + bev; vv.w = acc[3] + bev;
            *(float4*)(outp + ((size_t)(b * 256 + oo)) * NN + n0 + lg * 4) = vv;
        }
    }
}

extern "C" void kernel_launch(void* const* d_in, const int* in_sizes, int n_in,
                              void* d_out, int out_size, void* d_ws, size_t ws_size,
                              hipStream_t stream) {
    const float* key    = (const float*)d_in[0];
    const float* values = (const float*)d_in[1];
    const float* pos    = (const float*)d_in[2];
    const float* Wk     = (const float*)d_in[3];
    const float* bk     = (const float*)d_in[4];
    const float* Wq     = (const float*)d_in[5];
    const float* bq     = (const float*)d_in[6];
    const float* Wv     = (const float*)d_in[7];
    const float* bv     = (const float*)d_in[8];
    const float* Wp1    = (const float*)d_in[9];
    const float* bp1    = (const float*)d_in[10];
    const float* pg     = (const float*)d_in[11];
    const float* pb     = (const float*)d_in[12];
    const float* pm     = (const float*)d_in[13];
    const float* pv     = (const float*)d_in[14];
    const float* Wp2    = (const float*)d_in[15];
    const float* bp2    = (const float*)d_in[16];
    const float* Wa1    = (const float*)d_in[17];
    const float* ba1    = (const float*)d_in[18];
    const float* ag     = (const float*)d_in[19];
    const float* ab     = (const float*)d_in[20];
    const float* am     = (const float*)d_in[21];
    const float* av     = (const float*)d_in[22];
    const float* Wa2    = (const float*)d_in[23];
    const float* We     = (const float*)d_in[25];
    const float* be     = (const float*)d_in[26];
    (void)in_sizes; (void)n_in; (void)out_size; (void)ws_size;

    char* ws = (char*)d_ws;

    hipFuncSetAttribute((const void*)pt_main,
                        hipFuncAttributeMaxDynamicSharedMemorySize, LDS_TOTAL);

    hipLaunchKernelGGL(prep_sc, dim3(5), dim3(256), 0, stream,
                       ag, ab, am, av, ba1, Wp1, Wq, bq, bp1, pg, pb, pm, pv, ws);
    hipLaunchKernelGGL(prep_cvt, dim3(2560), dim3(256), 0, stream,
                       Wk, Wv, We, Wa1, Wa2, ws);
    hipLaunchKernelGGL(pt_main, dim3(1024), dim3(256), LDS_TOTAL, stream,
                       key, values, pos, Wq, bq, bk, bv, Wp2, bp2, be,
                       (const char*)ws, (float*)d_out);
}